// Round 9
// baseline (132.990 us; speedup 1.0000x reference)
//
#include <hip/hip_runtime.h>
#include <cstdint>
#include <cstddef>

typedef unsigned short u16;
typedef __attribute__((ext_vector_type(8))) short short8;
typedef __attribute__((ext_vector_type(4))) float f32x4;

#define CIN   512
#define COUT  512
#define BATCH 16
#define HWSZ  1024      // 32*32
#define PADW  34        // 32 + 2 halo

static constexpr float MOD_SCALE  = 0.044194173824159216f;   // 1/sqrt(512)
static constexpr float CONV_SCALE = 0.014731391274719739f;   // 1/sqrt(512*9)

// workspace layout (bytes)
#define WS_S    0                              // 8192 f32   (32 KB)
#define WS_DSC  (32*1024)                      // 8192 f32   (32 KB)
#define WS_WSQ  (64*1024)                      // 262144 f32 (1 MB)
#define WS_WBT  (64*1024 + 1024*1024)          // 9*512*512 bf16 (4.5 MB)
#define WS_XSP  (WS_WBT + 9*512*512*2)         // 16*34*34*512 bf16 (~18 MB)

__device__ __forceinline__ u16 f2bf(float f) {
  union { float f; uint32_t u; } v; v.f = f;
  uint32_t r = v.u + 0x7fffu + ((v.u >> 16) & 1u);   // RNE
  return (u16)(r >> 16);
}

__device__ __forceinline__ void gload16(const void* g, void* l) {
  __builtin_amdgcn_global_load_lds(
      (const __attribute__((address_space(1))) void*)g,
      (__attribute__((address_space(3))) void*)l, 16, 0, 0);
}

// ---------------- s[b,i] = mod_scale * style[b,:] . mod_w[i,:] + mod_b[i] ----------------
__global__ void k_style(const float* __restrict__ style, const float* __restrict__ mod_w,
                        const float* __restrict__ mod_b, float* __restrict__ s_out) {
  int gid  = blockIdx.x * blockDim.x + threadIdx.x;
  int w    = gid >> 6, lane = gid & 63;
  int b    = w >> 9, i = w & 511;
  const float4* st = (const float4*)(style + (size_t)b * 512);
  const float4* mw = (const float4*)(mod_w + (size_t)i * 512);
  float4 a0 = st[lane * 2], a1 = st[lane * 2 + 1];
  float4 w0 = mw[lane * 2], w1 = mw[lane * 2 + 1];
  float acc = a0.x*w0.x + a0.y*w0.y + a0.z*w0.z + a0.w*w0.w
            + a1.x*w1.x + a1.y*w1.y + a1.z*w1.z + a1.w*w1.w;
  #pragma unroll
  for (int off = 32; off; off >>= 1) acc += __shfl_xor(acc, off);
  if (lane == 0) s_out[w] = acc * MOD_SCALE + mod_b[i];
}

// ---- fused: wsq[o,i] = sum_k w^2 ; wbT[kxy][o][i] = bf16(w) ----
__global__ void k_wprep(const float* __restrict__ w, float* __restrict__ wsq,
                        u16* __restrict__ wbt) {
  int idx = blockIdx.x * 256 + threadIdx.x;          // 262144 = o*512+i
  const float* p = w + (size_t)idx * 9;
  float a = 0.f;
  #pragma unroll
  for (int kxy = 0; kxy < 9; ++kxy) {
    float v = p[kxy];
    a += v * v;
    wbt[(size_t)kxy * 262144 + idx] = f2bf(v);
  }
  wsq[idx] = a;
}

// ---------------- dscale[b,o] = conv_scale * rsqrt(cs^2 * sum_i wsq[o,i]*s[b,i]^2 + 1e-8) ----
__global__ void k_dscale(const float* __restrict__ wsq, const float* __restrict__ s,
                         float* __restrict__ dsc) {
  int gid  = blockIdx.x * blockDim.x + threadIdx.x;
  int w    = gid >> 6, lane = gid & 63;
  int b    = w >> 9, o = w & 511;
  const float4* q4 = (const float4*)(wsq + (size_t)o * 512);
  const float4* s4 = (const float4*)(s   + (size_t)b * 512);
  float4 q0 = q4[lane * 2], q1 = q4[lane * 2 + 1];
  float4 t0 = s4[lane * 2], t1 = s4[lane * 2 + 1];
  float acc = q0.x*t0.x*t0.x + q0.y*t0.y*t0.y + q0.z*t0.z*t0.z + q0.w*t0.w*t0.w
            + q1.x*t1.x*t1.x + q1.y*t1.y*t1.y + q1.z*t1.z*t1.z + q1.w*t1.w*t1.w;
  #pragma unroll
  for (int off = 32; off; off >>= 1) acc += __shfl_xor(acc, off);
  if (lane == 0)
    dsc[w] = CONV_SCALE * rsqrtf(acc * CONV_SCALE * CONV_SCALE + 1e-8f);
}

// ---------------- zero only the halo border of xs_p ----------------
__global__ void k_halo(u16* __restrict__ xsp) {
  int cell = blockIdx.x;      // 0..131 border cells of the 34x34 grid
  int b = blockIdx.y;
  int y, x;
  if (cell < 34)       { y = 0;          x = cell; }
  else if (cell < 68)  { y = 33;         x = cell - 34; }
  else if (cell < 100) { y = cell - 67;  x = 0; }    // 1..32
  else                 { y = cell - 99;  x = 33; }   // 1..32
  uint32_t* p = (uint32_t*)(xsp + ((size_t)(b * PADW + y) * PADW + x) * 512);
  p[threadIdx.x] = 0;   // 256 threads x 4B = 512 u16
}

// ---------------- xs_p[b][y+1][x+1][i] = bf16(x[b][i][y][x] * s[b][i])  (NCHW->NHWC) --------
__global__ void k_xs(const float* __restrict__ x, const float* __restrict__ s,
                     u16* __restrict__ xsp) {
  __shared__ float tile[64][33];
  int icb = blockIdx.x, y = blockIdx.y, b = blockIdx.z;
  int t = threadIdx.x;
  int i0 = icb * 64;
  int c  = t & 31;       // x coord
  int r0 = t >> 5;       // 0..7
  #pragma unroll
  for (int it = 0; it < 8; ++it) {
    int row = r0 + it * 8;                           // i_loc 0..63
    float sv = s[b * 512 + i0 + row];
    tile[row][c] = x[((size_t)(b * 512 + i0 + row)) * 1024 + y * 32 + c] * sv;
  }
  __syncthreads();
  int il = t & 63;
  int x0 = t >> 6;       // 0..3
  #pragma unroll
  for (int it = 0; it < 8; ++it) {
    int xc = x0 + it * 4;
    xsp[((size_t)((b * PADW + y + 1) * PADW) + (xc + 1)) * 512 + i0 + il] = f2bf(tile[il][xc]);
  }
}

// ---------------- implicit-GEMM conv + fused epilogue ----------------
// Tile 256(o) x 128(m), 8 waves (4o x 2m, per-wave 64x64), K=4608 in 72 tiles of 64.
// 8-PHASE-STYLE SCHEDULE (m201 port): each K-tile = 4 phases, each phase
//   { ds_read this phase's fragments (4-6 b128)  |  2 global_load_lds of tile t+2 }
//   -> s_barrier -> setprio(1) -> 8 MFMA (register-only) -> setprio(0) -> s_barrier
// Counted vmcnt(6) ONCE per K-tile (end of phase 3): stage(t+2) stays in flight
// across all barriers (T4, never 0 mid-loop). Tri-ring LDS (3 x 48 KB).
// T2 XOR swizzle (pre-swizzled global source + swizzled ds_read). T1 XCD swizzle.
__global__ __launch_bounds__(512, 1) void k_conv(
    const u16* __restrict__ wbt, const u16* __restrict__ xsp,
    const float* __restrict__ dsc, const float* __restrict__ noise,
    const float* __restrict__ nw, const float* __restrict__ abias,
    float* __restrict__ out)
{
  __shared__ u16 Ald[3 * 16384];   // 3 x 256x64 bf16 = 96 KB (swizzled)
  __shared__ u16 Bld[3 * 8192];    // 3 x 128x64 bf16 = 48 KB (swizzled)

  const int tid  = threadIdx.x;
  const int wave = tid >> 6, lane = tid & 63;

  // T1: XCD swizzle (grid 256 = 8 XCD x 32 contiguous tiles)
  const int bid = blockIdx.x;
  const int swz = (bid & 7) * 32 + (bid >> 3);
  const int o0 = (swz >> 7) << 8;     // 0 or 256
  const int m0 = (swz & 127) << 7;    // 0..16256
  const int b  = m0 >> 10;            // uniform per block

  const int wo = (wave >> 1) * 64;    // o sub-block: 0/64/128/192
  const int wm = (wave & 1) * 64;     // m sub-block: 0/64
  const int lrow = lane & 15;
  const int lk   = (lane >> 4) * 8;
  const int rsw  = (lrow & 7) << 3;   // read-side swizzle (u16 units)
  const int kos0 = lk ^ rsw;
  const int kos1 = (32 + lk) ^ rsw;

  // staging bases: lane covers row (base + lane>>3), 16-B chunk (lane&7);
  // swizzled source chunk = (lane&7) ^ (row&7)   [T2, write side via global src]
  const int cc = (((lane & 7) ^ (lane >> 3)) * 8);
  const u16* gA[4]; int lAo[4];
  #pragma unroll
  for (int q = 0; q < 4; ++q) {
    int r = wave * 32 + q * 8 + (lane >> 3);          // 0..255
    gA[q] = wbt + (size_t)(o0 + r) * 512 + cc;
    lAo[q] = (wave * 32 + q * 8) * 64;
  }
  const u16* gB[2]; int lBo[2];
  #pragma unroll
  for (int q = 0; q < 2; ++q) {
    int r = wave * 16 + q * 8 + (lane >> 3);          // 0..127
    int mg = m0 + r;
    int yy = (mg >> 5) & 31, xx = mg & 31;
    gB[q] = xsp + ((size_t)(b * PADW + yy) * PADW + xx) * 512 + cc;
    lBo[q] = (wave * 16 + q * 8) * 64;
  }

  f32x4 acc[4][4];
  #pragma unroll
  for (int i = 0; i < 4; ++i)
    #pragma unroll
    for (int j = 0; j < 4; ++j) acc[i][j] = (f32x4){0.f, 0.f, 0.f, 0.f};

  // stage helpers: 2 global_load_lds each (phase-sized chunks of tile ks)
  auto stgA = [&](int ks, int bufi, int q0) {
    int kxy = ks >> 3, ib = (ks & 7) << 6;
    int offA = kxy * 262144 + ib;
    gload16(gA[q0] + offA,     &Ald[bufi * 16384 + lAo[q0]]);
    gload16(gA[q0 + 1] + offA, &Ald[bufi * 16384 + lAo[q0 + 1]]);
  };
  auto stgB = [&](int ks, int bufi) {
    int kxy = ks >> 3, ib = (ks & 7) << 6;
    int ky = kxy / 3, kx = kxy - ky * 3;
    int offB = ((ky * PADW + kx) << 9) + ib;
    gload16(gB[0] + offB, &Bld[bufi * 8192 + lBo[0]]);
    gload16(gB[1] + offB, &Bld[bufi * 8192 + lBo[1]]);
  };

#define LDA(CA, MI, KOS) (*(const short8*)&Ald[(CA) + (wo + (MI) * 16 + lrow) * 64 + (KOS)])
#define LDB(CB, NI, KOS) (*(const short8*)&Bld[(CB) + (wm + (NI) * 16 + lrow) * 64 + (KOS)])

#define MFMA8(MI0)                                                        \
    _Pragma("unroll")                                                     \
    for (int ni = 0; ni < 4; ++ni) {                                      \
      acc[(MI0)][ni] = __builtin_amdgcn_mfma_f32_16x16x32_bf16(           \
          av0, bv[ni], acc[(MI0)][ni], 0, 0, 0);                          \
      acc[(MI0) + 1][ni] = __builtin_amdgcn_mfma_f32_16x16x32_bf16(       \
          av1, bv[ni], acc[(MI0) + 1][ni], 0, 0, 0);                      \
    }

  // One K-tile = 4 phases. Stage of tile KS2 spread over phases 0-2 (2+2+2).
  // vmcnt at end of phase 3: in-flight {stage(t+1)=6, stage(t+2)=6} -> vmcnt(6)
  // drains stage(t+1) (next tile's data ready), leaves stage(t+2) in flight.
#define KTILE(CUR, NXT, KS2, DOSTG, VM)                                   \
  {                                                                       \
    const int ca = (CUR) * 16384, cb = (CUR) * 8192;                      \
    short8 av0, av1, bv[4];                                               \
    /* phase 0: kh0, mi 0-1 */                                            \
    av0 = LDA(ca, 0, kos0); av1 = LDA(ca, 1, kos0);                       \
    bv[0] = LDB(cb, 0, kos0); bv[1] = LDB(cb, 1, kos0);                   \
    bv[2] = LDB(cb, 2, kos0); bv[3] = LDB(cb, 3, kos0);                   \
    if (DOSTG) stgA(KS2, NXT, 0);                                         \
    __builtin_amdgcn_s_barrier();                                         \
    __builtin_amdgcn_s_setprio(1);                                        \
    MFMA8(0);                                                             \
    __builtin_amdgcn_s_setprio(0);                                        \
    __builtin_amdgcn_s_barrier();                                         \
    /* phase 1: kh0, mi 2-3 (bv reused) */                                \
    av0 = LDA(ca, 2, kos0); av1 = LDA(ca, 3, kos0);                       \
    if (DOSTG) stgA(KS2, NXT, 2);                                         \
    __builtin_amdgcn_s_barrier();                                         \
    __builtin_amdgcn_s_setprio(1);                                        \
    MFMA8(2);                                                             \
    __builtin_amdgcn_s_setprio(0);                                        \
    __builtin_amdgcn_s_barrier();                                         \
    /* phase 2: kh1, mi 0-1 */                                            \
    av0 = LDA(ca, 0, kos1); av1 = LDA(ca, 1, kos1);                       \
    bv[0] = LDB(cb, 0, kos1); bv[1] = LDB(cb, 1, kos1);                   \
    bv[2] = LDB(cb, 2, kos1); bv[3] = LDB(cb, 3, kos1);                   \
    if (DOSTG) stgB(KS2, NXT);                                            \
    __builtin_amdgcn_s_barrier();                                         \
    __builtin_amdgcn_s_setprio(1);                                        \
    MFMA8(0);                                                             \
    __builtin_amdgcn_s_setprio(0);                                        \
    __builtin_amdgcn_s_barrier();                                         \
    /* phase 3: kh1, mi 2-3 (bv reused); end-of-tile vmcnt */             \
    av0 = LDA(ca, 2, kos1); av1 = LDA(ca, 3, kos1);                       \
    __builtin_amdgcn_s_barrier();                                         \
    __builtin_amdgcn_s_setprio(1);                                        \
    MFMA8(2);                                                             \
    __builtin_amdgcn_s_setprio(0);                                        \
    asm volatile("s_waitcnt vmcnt(" #VM ")" ::: "memory");                \
    __builtin_amdgcn_s_barrier();                                         \
  }

  // prologue: tiles 0,1 fully staged; wait tile 0 (vmcnt(6): tile 1 in flight)
  stgA(0, 0, 0); stgA(0, 0, 2); stgB(0, 0);
  stgA(1, 1, 0); stgA(1, 1, 2); stgB(1, 1);
  asm volatile("s_waitcnt vmcnt(6)" ::: "memory");
  __builtin_amdgcn_s_barrier();

  for (int t = 0; t < 23; ++t) {
    const int k0 = t * 3;
    KTILE(0, 2, k0 + 2, 1, 6);
    KTILE(1, 0, k0 + 3, 1, 6);
    KTILE(2, 1, k0 + 4, 1, 6);
  }
  // tail: tiles 69..71
  KTILE(0, 2, 71, 1, 6);   // tile 69: stage tile 71 -> buf2
  KTILE(1, 0, 0, 0, 0);    // tile 70: drain stage(71)
  KTILE(2, 1, 0, 0, 0);    // tile 71
#undef KTILE
#undef MFMA8
#undef LDA
#undef LDB

  // epilogue: demod*conv_scale, noise, bias, leaky(0.2)*sqrt(2)
  const float nwv = nw[0];
  const int mrow = (lane >> 4) << 2;
  #pragma unroll
  for (int mi = 0; mi < 4; ++mi) {
    #pragma unroll
    for (int ni = 0; ni < 4; ++ni) {
      int mg = m0 + wm + ni * 16 + lrow;
      int hw = mg & 1023;
      float nz = nwv * noise[b * 1024 + hw];
      #pragma unroll
      for (int r = 0; r < 4; ++r) {
        int og = o0 + wo + mi * 16 + mrow + r;
        float v = acc[mi][ni][r] * dsc[b * 512 + og] + nz + abias[og];
        v = (v > 0.f ? v : 0.2f * v) * 1.4142135623730951f;
        out[(size_t)(b * 512 + og) * 1024 + hw] = v;
      }
    }
  }
}

extern "C" void kernel_launch(void* const* d_in, const int* in_sizes, int n_in,
                              void* d_out, int out_size, void* d_ws, size_t ws_size,
                              hipStream_t stream) {
  const float* x      = (const float*)d_in[0];
  const float* style  = (const float*)d_in[1];
  const float* noise  = (const float*)d_in[2];
  const float* weight = (const float*)d_in[3];
  const float* mod_w  = (const float*)d_in[4];
  const float* mod_b  = (const float*)d_in[5];
  const float* nw     = (const float*)d_in[6];
  const float* abias  = (const float*)d_in[7];
  float* out = (float*)d_out;

  char* ws = (char*)d_ws;
  float* s_buf = (float*)(ws + WS_S);
  float* dsc   = (float*)(ws + WS_DSC);
  float* wsq   = (float*)(ws + WS_WSQ);
  u16*   wbt   = (u16*)(ws + WS_WBT);
  u16*   xsp   = (u16*)(ws + WS_XSP);

  k_halo  <<<dim3(132, 16), 256, 0, stream>>>(xsp);
  k_style <<<2048, 256, 0, stream>>>(style, mod_w, mod_b, s_buf);
  k_wprep <<<1024, 256, 0, stream>>>(weight, wsq, wbt);
  k_dscale<<<2048, 256, 0, stream>>>(wsq, s_buf, dsc);
  k_xs    <<<dim3(8, 32, 16), 256, 0, stream>>>(x, s_buf, xsp);
  k_conv  <<<256, 512, 0, stream>>>(wbt, xsp, dsc, noise, nw, abias, out);
}

// Round 10
// 116.987 us; speedup vs baseline: 1.1368x; 1.1368x over previous
//
#include <hip/hip_runtime.h>
#include <cstdint>
#include <cstddef>

typedef unsigned short u16;
typedef __attribute__((ext_vector_type(8))) short short8;
typedef __attribute__((ext_vector_type(4))) float f32x4;

#define CIN   512
#define COUT  512
#define BATCH 16
#define HWSZ  1024      // 32*32
#define PADW  34        // 32 + 2 halo

static constexpr float MOD_SCALE  = 0.044194173824159216f;   // 1/sqrt(512)
static constexpr float CONV_SCALE = 0.014731391274719739f;   // 1/sqrt(512*9)

// workspace layout (bytes)
#define WS_S    0                              // 8192 f32   (32 KB)
#define WS_DSC  (32*1024)                      // 8192 f32   (32 KB)
#define WS_WSQ  (64*1024)                      // 262144 f32 (1 MB)
#define WS_WBT  (64*1024 + 1024*1024)          // 9*512*512 bf16 (4.5 MB)
#define WS_XSP  (WS_WBT + 9*512*512*2)         // 16*34*34*512 bf16 (~18 MB)

__device__ __forceinline__ u16 f2bf(float f) {
  union { float f; uint32_t u; } v; v.f = f;
  uint32_t r = v.u + 0x7fffu + ((v.u >> 16) & 1u);   // RNE
  return (u16)(r >> 16);
}

// ---------------- s[b,i] = mod_scale * style[b,:] . mod_w[i,:] + mod_b[i] ----------------
__global__ void k_style(const float* __restrict__ style, const float* __restrict__ mod_w,
                        const float* __restrict__ mod_b, float* __restrict__ s_out) {
  int gid  = blockIdx.x * blockDim.x + threadIdx.x;
  int w    = gid >> 6, lane = gid & 63;
  int b    = w >> 9, i = w & 511;
  const float4* st = (const float4*)(style + (size_t)b * 512);
  const float4* mw = (const float4*)(mod_w + (size_t)i * 512);
  float4 a0 = st[lane * 2], a1 = st[lane * 2 + 1];
  float4 w0 = mw[lane * 2], w1 = mw[lane * 2 + 1];
  float acc = a0.x*w0.x + a0.y*w0.y + a0.z*w0.z + a0.w*w0.w
            + a1.x*w1.x + a1.y*w1.y + a1.z*w1.z + a1.w*w1.w;
  #pragma unroll
  for (int off = 32; off; off >>= 1) acc += __shfl_xor(acc, off);
  if (lane == 0) s_out[w] = acc * MOD_SCALE + mod_b[i];
}

// ---- fused: wsq[o,i] = sum_k w^2 ; wbt2[((kxy*64 + i/8)*512 + o)*8 + i%8] = bf16(w) ----
__global__ void k_wprep(const float* __restrict__ w, float* __restrict__ wsq,
                        u16* __restrict__ wbt2) {
  int idx = blockIdx.x * 256 + threadIdx.x;          // 262144 = o*512+i
  int o = idx >> 9, i = idx & 511;
  const float* p = w + (size_t)idx * 9;
  float a = 0.f;
  #pragma unroll
  for (int kxy = 0; kxy < 9; ++kxy) {
    float v = p[kxy];
    a += v * v;
    wbt2[((size_t)(kxy * 64 + (i >> 3)) * 512 + o) * 8 + (i & 7)] = f2bf(v);
  }
  wsq[idx] = a;
}

// ---------------- dscale[b,o] = conv_scale * rsqrt(cs^2 * sum_i wsq[o,i]*s[b,i]^2 + 1e-8) ----
__global__ void k_dscale(const float* __restrict__ wsq, const float* __restrict__ s,
                         float* __restrict__ dsc) {
  int gid  = blockIdx.x * blockDim.x + threadIdx.x;
  int w    = gid >> 6, lane = gid & 63;
  int b    = w >> 9, o = w & 511;
  const float4* q4 = (const float4*)(wsq + (size_t)o * 512);
  const float4* s4 = (const float4*)(s   + (size_t)b * 512);
  float4 q0 = q4[lane * 2], q1 = q4[lane * 2 + 1];
  float4 t0 = s4[lane * 2], t1 = s4[lane * 2 + 1];
  float acc = q0.x*t0.x*t0.x + q0.y*t0.y*t0.y + q0.z*t0.z*t0.z + q0.w*t0.w*t0.w
            + q1.x*t1.x*t1.x + q1.y*t1.y*t1.y + q1.z*t1.z*t1.z + q1.w*t1.w*t1.w;
  #pragma unroll
  for (int off = 32; off; off >>= 1) acc += __shfl_xor(acc, off);
  if (lane == 0)
    dsc[w] = CONV_SCALE * rsqrtf(acc * CONV_SCALE * CONV_SCALE + 1e-8f);
}

// ---------------- zero only the halo border of xs_p ----------------
__global__ void k_halo(u16* __restrict__ xsp) {
  int cell = blockIdx.x;      // 0..131 border cells of the 34x34 grid
  int b = blockIdx.y;
  int y, x;
  if (cell < 34)       { y = 0;          x = cell; }
  else if (cell < 68)  { y = 33;         x = cell - 34; }
  else if (cell < 100) { y = cell - 67;  x = 0; }    // 1..32
  else                 { y = cell - 99;  x = 33; }   // 1..32
  uint32_t* p = (uint32_t*)(xsp + ((size_t)(b * PADW + y) * PADW + x) * 512);
  p[threadIdx.x] = 0;   // 256 threads x 4B = 512 u16
}

// ---------------- xs_p[b][y+1][x+1][i] = bf16(x[b][i][y][x] * s[b][i])  (NCHW->NHWC) --------
__global__ void k_xs(const float* __restrict__ x, const float* __restrict__ s,
                     u16* __restrict__ xsp) {
  __shared__ float tile[64][33];
  int icb = blockIdx.x, y = blockIdx.y, b = blockIdx.z;
  int t = threadIdx.x;
  int i0 = icb * 64;
  int c  = t & 31;       // x coord
  int r0 = t >> 5;       // 0..7
  #pragma unroll
  for (int it = 0; it < 8; ++it) {
    int row = r0 + it * 8;                           // i_loc 0..63
    float sv = s[b * 512 + i0 + row];
    tile[row][c] = x[((size_t)(b * 512 + i0 + row)) * 1024 + y * 32 + c] * sv;
  }
  __syncthreads();
  int il = t & 63;
  int x0 = t >> 6;       // 0..3
  #pragma unroll
  for (int it = 0; it < 8; ++it) {
    int xc = x0 + it * 4;
    xsp[((size_t)((b * PADW + y + 1) * PADW) + (xc + 1)) * 512 + i0 + il] = f2bf(tile[il][xc]);
  }
}

// ---------------- implicit-GEMM conv + fused epilogue (halo-reuse, barrier-free) ---------
// Tile 256(o) x 128(m), 8 waves (4o x 2m, per-wave 64x64). K = 8 passes (i-chunks
// of 64) x 9 kxy taps. Per pass: the block's 6x36x64 input halo is staged ONCE
// into double-buffered LDS (reg-staged from xsp, chunk XOR-swizzled); all 9
// K-tiles read B from it at (ky,kx) offsets. A streams global->VGPR directly,
// double-banked 1 tile ahead (weights L2-resident per XCD, T1 swizzle).
// NO barriers inside a pass; only 8 pass-boundary lgkmcnt(0)+s_barrier total.
// All loads are register-tracked -> compiler manages vmcnt/lgkmcnt; waves self-pace.
__global__ __launch_bounds__(512, 1) void k_conv(
    const u16* __restrict__ wbt2, const u16* __restrict__ xsp,
    const float* __restrict__ dsc, const float* __restrict__ noise,
    const float* __restrict__ nw, const float* __restrict__ abias,
    float* __restrict__ out)
{
  __shared__ u16 H[2][13824];   // [6 yy][36 xx][64 i] bf16, double-buffered (54 KB)

  const int tid  = threadIdx.x;
  const int wave = tid >> 6, lane = tid & 63;

  // T1: XCD swizzle (grid 256 = 8 XCD x 32 contiguous tiles)
  const int bid = blockIdx.x;
  const int swz = (bid & 7) * 32 + (bid >> 3);
  const int o0 = (swz >> 7) << 8;     // 0 or 256
  const int m0 = (swz & 127) << 7;    // 0..16256
  const int b  = m0 >> 10;            // uniform per block
  const int y0 = (m0 & 1023) >> 5;    // first y row of the block's m-window

  const int wo = (wave >> 1) * 64;    // o sub-block: 0/64/128/192
  const int wm = (wave & 1) * 64;     // m sub-block: 0/64
  const int lrow = lane & 15;
  const int g    = lane >> 4;         // k-chunk group 0..3

  // ---- A stream base (wbt2 fragment layout) ----
  // addr(P,kxy,kh,mi) = pA + kxy*262144 + P*32768 + kh*16384 + mi*128
  const u16* pA = wbt2 + (size_t)g * 4096 + (size_t)(o0 + wo + lrow) * 8;

  // ---- bv byte offsets into a halo buffer: offs[ni][kx][kh] (+ ky*4608 + buf*27648) ----
  int offs[4][3][2];
  #pragma unroll
  for (int ni = 0; ni < 4; ++ni) {
    int mloc = wm + ni * 16 + lrow;
    int yb = mloc >> 5, xb = mloc & 31;
    #pragma unroll
    for (int kx = 0; kx < 3; ++kx) {
      int xx = xb + kx;
      #pragma unroll
      for (int kh = 0; kh < 2; ++kh) {
        int c = (kh * 4 + g) ^ (xx & 7);          // chunk XOR swizzle (match write)
        offs[ni][kx][kh] = (((yb * 36 + xx) * 64) + c * 8) * 2;
      }
    }
  }

  // ---- halo staging tasks: 1632 = 6 yy x 34 xx x 8 chunks; 4 rounds x 512 lanes ----
  int hsrc[4], hdst[4];
  bool hval[4];
  #pragma unroll
  for (int r = 0; r < 4; ++r) {
    int T = r * 512 + wave * 64 + lane;
    hval[r] = (T < 1632);
    int Tc = hval[r] ? T : 0;
    int yy = Tc / 272, rem = Tc % 272;            // 272 = 34*8
    int xx = rem >> 3, c = rem & 7;
    hsrc[r] = ((b * 34 + y0 + yy) * 34 + xx) * 512 + c * 8;   // + P*64 at use
    hdst[r] = (yy * 36 + xx) * 64 + ((c ^ (xx & 7)) * 8);     // u16 idx in H[buf]
  }

  f32x4 acc[4][4];
  #pragma unroll
  for (int i = 0; i < 4; ++i)
    #pragma unroll
    for (int j = 0; j < 4; ++j) acc[i][j] = (f32x4){0.f, 0.f, 0.f, 0.f};

  short8 av0[2][4], av1[2][4];   // double-banked A fragments
  short8 hv[4];                  // in-flight halo data (pass p+1)

#define AVLOAD(NP, NK, DST)                                               \
  { const u16* ab = pA + (NK) * 262144 + (NP) * 32768;                    \
    _Pragma("unroll")                                                     \
    for (int kh = 0; kh < 2; ++kh)                                        \
      _Pragma("unroll")                                                   \
      for (int mi = 0; mi < 4; ++mi)                                      \
        DST[kh][mi] = *(const short8*)(ab + kh * 16384 + mi * 128); }

  // TILE: optionally issue halo loads (pass PP+1) / halo writes / next avload,
  // then read bv from H[HC] at (ky,kx) and run 32 MFMA from registers.
#define TILE(PP, KXY, AVC, AVN, HC, HN, DOLD, DOH0, DOH4)                 \
  {                                                                       \
    if (DOH0) {                                                           \
      _Pragma("unroll")                                                   \
      for (int r = 0; r < 4; ++r)                                         \
        if (hval[r])                                                      \
          hv[r] = *(const short8*)(xsp + hsrc[r] + ((PP) + 1) * 64);      \
    }                                                                     \
    if (DOH4) {                                                           \
      _Pragma("unroll")                                                   \
      for (int r = 0; r < 4; ++r)                                         \
        if (hval[r]) *(short8*)&H[HN][hdst[r]] = hv[r];                   \
    }                                                                     \
    if (DOLD) {                                                           \
      const int NP = ((KXY) < 8) ? (PP) : (PP) + 1;                       \
      const int NK = ((KXY) < 8) ? (KXY) + 1 : 0;                         \
      AVLOAD(NP, NK, AVN);                                                \
    }                                                                     \
    {                                                                     \
      const int ky = (KXY) / 3, kx = (KXY) % 3;                           \
      const char* hb = (const char*)&H[HC][0] + ky * 4608;                \
      short8 bv[4];                                                       \
      _Pragma("unroll")                                                   \
      for (int ni = 0; ni < 4; ++ni)                                      \
        bv[ni] = *(const short8*)(hb + offs[ni][kx][0]);                  \
      _Pragma("unroll")                                                   \
      for (int mi = 0; mi < 4; ++mi)                                      \
        _Pragma("unroll")                                                 \
        for (int ni = 0; ni < 4; ++ni)                                    \
          acc[mi][ni] = __builtin_amdgcn_mfma_f32_16x16x32_bf16(          \
              AVC[0][mi], bv[ni], acc[mi][ni], 0, 0, 0);                  \
      _Pragma("unroll")                                                   \
      for (int ni = 0; ni < 4; ++ni)                                      \
        bv[ni] = *(const short8*)(hb + offs[ni][kx][1]);                  \
      _Pragma("unroll")                                                   \
      for (int mi = 0; mi < 4; ++mi)                                      \
        _Pragma("unroll")                                                 \
        for (int ni = 0; ni < 4; ++ni)                                    \
          acc[mi][ni] = __builtin_amdgcn_mfma_f32_16x16x32_bf16(          \
              AVC[1][mi], bv[ni], acc[mi][ni], 0, 0, 0);                  \
    }                                                                     \
  }

  // PASS: 9 tiles, halo loads at tile 0, halo writes at tile 4, one barrier at end.
#define PASS(PP, HC, HN, A, B, DOSTG, DOLDLAST)                           \
  TILE(PP, 0, A, B, HC, HN, 1, DOSTG, 0)                                  \
  TILE(PP, 1, B, A, HC, HN, 1, 0, 0)                                      \
  TILE(PP, 2, A, B, HC, HN, 1, 0, 0)                                      \
  TILE(PP, 3, B, A, HC, HN, 1, 0, 0)                                      \
  TILE(PP, 4, A, B, HC, HN, 1, 0, DOSTG)                                  \
  TILE(PP, 5, B, A, HC, HN, 1, 0, 0)                                      \
  TILE(PP, 6, A, B, HC, HN, 1, 0, 0)                                      \
  TILE(PP, 7, B, A, HC, HN, 1, 0, 0)                                      \
  TILE(PP, 8, A, B, HC, HN, DOLDLAST, 0, 0)                               \
  asm volatile("s_waitcnt lgkmcnt(0)" ::: "memory");                      \
  __builtin_amdgcn_s_barrier();

  // prologue: stage halo[0] (pass 0) and A(0,0)
  #pragma unroll
  for (int r = 0; r < 4; ++r)
    if (hval[r]) hv[r] = *(const short8*)(xsp + hsrc[r]);   // P=0
  #pragma unroll
  for (int r = 0; r < 4; ++r)
    if (hval[r]) *(short8*)&H[0][hdst[r]] = hv[r];
  AVLOAD(0, 0, av0);
  asm volatile("s_waitcnt lgkmcnt(0)" ::: "memory");
  __builtin_amdgcn_s_barrier();

  // passes 0..5 (runtime pp, static parity via paired bodies)
  for (int pp = 0; pp < 6; pp += 2) {
    PASS(pp,     0, 1, av0, av1, 1, 1)
    PASS(pp + 1, 1, 0, av1, av0, 1, 1)
  }
  PASS(6, 0, 1, av0, av1, 1, 1)
  PASS(7, 1, 0, av1, av0, 0, 0)
#undef PASS
#undef TILE
#undef AVLOAD

  // epilogue: demod*conv_scale, noise, bias, leaky(0.2)*sqrt(2)
  const float nwv = nw[0];
  const int mrow = (lane >> 4) << 2;
  #pragma unroll
  for (int mi = 0; mi < 4; ++mi) {
    #pragma unroll
    for (int ni = 0; ni < 4; ++ni) {
      int mg = m0 + wm + ni * 16 + lrow;
      int hw = mg & 1023;
      float nz = nwv * noise[b * 1024 + hw];
      #pragma unroll
      for (int r = 0; r < 4; ++r) {
        int og = o0 + wo + mi * 16 + mrow + r;
        float v = acc[mi][ni][r] * dsc[b * 512 + og] + nz + abias[og];
        v = (v > 0.f ? v : 0.2f * v) * 1.4142135623730951f;
        out[(size_t)(b * 512 + og) * 1024 + hw] = v;
      }
    }
  }
}

extern "C" void kernel_launch(void* const* d_in, const int* in_sizes, int n_in,
                              void* d_out, int out_size, void* d_ws, size_t ws_size,
                              hipStream_t stream) {
  const float* x      = (const float*)d_in[0];
  const float* style  = (const float*)d_in[1];
  const float* noise  = (const float*)d_in[2];
  const float* weight = (const float*)d_in[3];
  const float* mod_w  = (const float*)d_in[4];
  const float* mod_b  = (const float*)d_in[5];
  const float* nw     = (const float*)d_in[6];
  const float* abias  = (const float*)d_in[7];
  float* out = (float*)d_out;

  char* ws = (char*)d_ws;
  float* s_buf = (float*)(ws + WS_S);
  float* dsc   = (float*)(ws + WS_DSC);
  float* wsq   = (float*)(ws + WS_WSQ);
  u16*   wbt2  = (u16*)(ws + WS_WBT);
  u16*   xsp   = (u16*)(ws + WS_XSP);

  k_halo  <<<dim3(132, 16), 256, 0, stream>>>(xsp);
  k_style <<<2048, 256, 0, stream>>>(style, mod_w, mod_b, s_buf);
  k_wprep <<<1024, 256, 0, stream>>>(weight, wsq, wbt2);
  k_dscale<<<2048, 256, 0, stream>>>(wsq, s_buf, dsc);
  k_xs    <<<dim3(8, 32, 16), 256, 0, stream>>>(x, s_buf, xsp);
  k_conv  <<<256, 512, 0, stream>>>(wbt2, xsp, dsc, noise, nw, abias, out);
}